// Round 2
// baseline (51.656 us; speedup 1.0000x reference)
//
#include <hip/hip_runtime.h>
#include <hip/hip_bf16.h>

typedef short  short8 __attribute__((ext_vector_type(8)));
typedef float  f32x4  __attribute__((ext_vector_type(4)));

#define B_N     2048
#define KLTOT   2048
#define NCHUNK  32
#define CHUNK_ROWS 64      // B_N / NCHUNK

// ---- workspace layout (float-sized slots) ----
#define WS_PART  0                         // 32*2048*2        = 131072
#define WS_W2F   (WS_PART + 131072)        // 2048*256 uints   = 524288
#define WS_W1F   (WS_W2F + 524288)        // 2048*32          = 65536
#define WS_B1F   (WS_W1F + 65536)         // 2048*32          = 65536
#define WS_W3P   (WS_B1F + 65536)         // 2048*16          = 32768
#define WS_B2P   (WS_W3P + 32768)         // 2048*16          = 32768
#define WS_MU    (WS_B2P + 32768)         // 2048
#define WS_RS    (WS_MU + 2048)           // 2048

__device__ __forceinline__ unsigned int bfb(float f) {
    union { __hip_bfloat16 h; unsigned short u; } cv;
    cv.h = __float2bfloat16(f);
    return (unsigned int)cv.u;
}

// ---------------- stats: partial sums over batch chunks (float4 cols) ----------------
__global__ __launch_bounds__(256) void stats_partial(const float* __restrict__ x,
                                                     float* __restrict__ part) {
    int c4 = blockIdx.x * 256 + threadIdx.x;          // 0..511 (col groups of 4)
    int chunk = blockIdx.y;
    const float4* p = (const float4*)(x + (size_t)(chunk * CHUNK_ROWS) * KLTOT) + c4;
    float4 s = {0.f, 0.f, 0.f, 0.f}, s2 = {0.f, 0.f, 0.f, 0.f};
#pragma unroll 8
    for (int r = 0; r < CHUNK_ROWS; ++r) {
        float4 v = p[(size_t)r * (KLTOT / 4)];
        s.x += v.x; s.y += v.y; s.z += v.z; s.w += v.w;
        s2.x = fmaf(v.x, v.x, s2.x); s2.y = fmaf(v.y, v.y, s2.y);
        s2.z = fmaf(v.z, v.z, s2.z); s2.w = fmaf(v.w, v.w, s2.w);
    }
    size_t base = ((size_t)chunk * KLTOT + (size_t)c4 * 4) * 2;
    part[base + 0] = s.x;  part[base + 1] = s2.x;
    part[base + 2] = s.y;  part[base + 3] = s2.y;
    part[base + 4] = s.z;  part[base + 5] = s2.z;
    part[base + 6] = s.w;  part[base + 7] = s2.w;
}

// ---------------- prep: finalize stats + pack MFMA-ready weight fragments ----------------
// one wave per kl column; grid 512 blocks x 256 thr
__global__ __launch_bounds__(256) void prep(
    const float* __restrict__ part,
    const float* __restrict__ W1, const float* __restrict__ b1,
    const float* __restrict__ W2, const float* __restrict__ b2,
    const float* __restrict__ W3,
    unsigned int* __restrict__ W2f, float* __restrict__ W1f, float* __restrict__ b1f,
    float* __restrict__ W3p, float* __restrict__ b2p,
    float* __restrict__ muA, float* __restrict__ rsA)
{
    __shared__ float sW2[4][224];
    const int tid = threadIdx.x;
    const int wv = tid >> 6, l = tid & 63;
    const int col = blockIdx.x * 4 + wv;

    // ---- stats finalize (butterfly over 32 chunks, halves duplicated) ----
    {
        int ch = l & 31;
        float s  = part[((size_t)ch * KLTOT + col) * 2 + 0];
        float s2 = part[((size_t)ch * KLTOT + col) * 2 + 1];
        for (int m = 1; m < 32; m <<= 1) {
            s  += __shfl_xor(s,  m, 64);
            s2 += __shfl_xor(s2, m, 64);
        }
        if (l == 0) {
            float mu  = s / (float)B_N;
            float var = fmaxf(s2 / (float)B_N - mu * mu, 0.f);
            muA[col] = mu;
            rsA[col] = 1.f / (sqrtf(var) + 1e-8f);
        }
    }

    // ---- stage this column's W2 (18x12 = 216 floats = 54 float4) ----
    const float* w2c = W2 + (size_t)col * 216;
    if (l < 54) *(float4*)&sW2[wv][l * 4] = ((const float4*)w2c)[l];
    __syncthreads();

    // ---- W2^T fragment: elem (g,j,e) = W2[h=g*8+e][j], zero-padded; packed 2x bf16/dword ----
    // dword d (0..255): ushort idx 2d,2d+1 ; idx: g=idx>>7, j=(idx>>3)&15, e=idx&7
#pragma unroll
    for (int q = 0; q < 4; ++q) {
        int d = q * 64 + l;
        unsigned int u[2];
#pragma unroll
        for (int half = 0; half < 2; ++half) {
            int idx = d * 2 + half;
            int g = idx >> 7, j = (idx >> 3) & 15, e = idx & 7;
            int h = g * 8 + e;
            float v = (h < 18 && j < 12) ? sW2[wv][h * 12 + j] : 0.f;
            u[half] = bfb(v);
        }
        W2f[(size_t)col * 256 + d] = u[0] | (u[1] << 16);
    }

    // ---- padded f32 copies of W1/b1 (18->32) and W3/b2 (12->16) ----
    if (l < 32) {
        W1f[(size_t)col * 32 + l] = (l < 18) ? W1[(size_t)col * 18 + l] : 0.f;
        b1f[(size_t)col * 32 + l] = (l < 18) ? b1[(size_t)col * 18 + l] : 0.f;
    }
    if (l < 16) {
        W3p[(size_t)col * 16 + l] = (l < 12) ? W3[(size_t)col * 12 + l] : 0.f;
        b2p[(size_t)col * 16 + l] = (l < 12) ? b2[(size_t)col * 12 + l] : 0.f;
    }
}

// ---------------- main MFMA kernel ----------------
// block = 256 thr (4 waves). tile: 64 cols x 64 rows. wave: 16 cols x 4 rowblocks of 16.
// per (col, rowblock): D = W2^T(16j x 32h) * h1^T(32h x 16rows)  [swapped operands]
__global__ __launch_bounds__(256) void mlp_mfma(
    const float* __restrict__ x,
    const unsigned int* __restrict__ W2f,
    const float* __restrict__ W1f, const float* __restrict__ b1f,
    const float* __restrict__ W3p, const float* __restrict__ b2p,
    const float* __restrict__ b3,
    const float* __restrict__ muA, const float* __restrict__ rsA,
    float* __restrict__ out)
{
    __shared__ float sxs[64 * 65];
    const int tid = threadIdx.x;
    const int kl0 = blockIdx.x * 64;
    const int b0  = blockIdx.y * 64;

    // ---- stage standardized x tile [64 cols][64 rows], padded stride 65 ----
    {
        int c = tid & 63, r0 = tid >> 6;
        float mu = muA[kl0 + c], rs = rsA[kl0 + c];
        const float* xp = x + (size_t)b0 * KLTOT + kl0 + c;
#pragma unroll
        for (int i = 0; i < 16; ++i) {
            int r = i * 4 + r0;
            sxs[c * 65 + r] = (xp[(size_t)r * KLTOT] - mu) * rs;
        }
    }
    __syncthreads();

    const int w = tid >> 6, l = tid & 63;
    const int g = l >> 4, lj = l & 15;

    for (int cc = 0; cc < 16; ++cc) {
        const int col = kl0 + w * 16 + cc;

        // A-operand: W2^T fragment (lane: row j=lj, k h=(g)*8+e)
        short8 afrag = *(const short8*)(W2f + (size_t)col * 256 + (g * 16 + lj) * 4);

        // per-lane W1/b1 for its h-range (f32, zero-padded)
        f32x4 w1a = *(const f32x4*)(W1f + (size_t)col * 32 + g * 8);
        f32x4 w1b = *(const f32x4*)(W1f + (size_t)col * 32 + g * 8 + 4);
        f32x4 b1a = *(const f32x4*)(b1f + (size_t)col * 32 + g * 8);
        f32x4 b1b = *(const f32x4*)(b1f + (size_t)col * 32 + g * 8 + 4);
        // epilogue constants: j = g*4 + r
        f32x4 w3r = *(const f32x4*)(W3p + (size_t)col * 16 + g * 4);
        f32x4 b2r = *(const f32x4*)(b2p + (size_t)col * 16 + g * 4);
        float b3v = b3[col];

        const float* xsb = &sxs[(w * 16 + cc) * 65 + lj];

#pragma unroll
        for (int rb = 0; rb < 4; ++rb) {
            float xsv = xsb[rb * 16];     // broadcast ds_read (16 banks, 4-way dup)

            // build h1 fragment: h1[row=lj][h=g*8+e], bf16
            float h1v[8];
#pragma unroll
            for (int e = 0; e < 4; ++e) h1v[e]     = fmaxf(fmaf(xsv, w1a[e], b1a[e]), 0.f);
#pragma unroll
            for (int e = 0; e < 4; ++e) h1v[4 + e] = fmaxf(fmaf(xsv, w1b[e], b1b[e]), 0.f);
            unsigned int bu[4];
#pragma unroll
            for (int q = 0; q < 4; ++q) bu[q] = bfb(h1v[2 * q]) | (bfb(h1v[2 * q + 1]) << 16);
            short8 bfrag;
            {
                union { unsigned int u[4]; short8 s; } cv;
                cv.u[0] = bu[0]; cv.u[1] = bu[1]; cv.u[2] = bu[2]; cv.u[3] = bu[3];
                bfrag = cv.s;
            }

            f32x4 acc = {0.f, 0.f, 0.f, 0.f};
            acc = __builtin_amdgcn_mfma_f32_16x16x32_bf16(afrag, bfrag, acc, 0, 0, 0);

            // out partial: sum over this lane's 4 j's
            float p = 0.f;
#pragma unroll
            for (int r = 0; r < 4; ++r) {
                float t = fmaxf(acc[r] + b2r[r], 0.f);
                p = fmaf(t, w3r[r], p);
            }
            // reduce across the 4 lane-groups (same batch row lj)
            p += __shfl_xor(p, 16, 64);
            p += __shfl_xor(p, 32, 64);

            if (l < 16)
                out[(size_t)(b0 + rb * 16 + lj) * KLTOT + col] = p + b3v;
        }
    }
}

extern "C" void kernel_launch(void* const* d_in, const int* in_sizes, int n_in,
                              void* d_out, int out_size, void* d_ws, size_t ws_size,
                              hipStream_t stream) {
    const float* x  = (const float*)d_in[0];
    const float* W1 = (const float*)d_in[1];
    const float* b1 = (const float*)d_in[2];
    const float* W2 = (const float*)d_in[3];
    const float* b2 = (const float*)d_in[4];
    const float* W3 = (const float*)d_in[5];
    const float* b3 = (const float*)d_in[6];
    float* out = (float*)d_out;

    float* ws = (float*)d_ws;
    float*        part = ws + WS_PART;
    unsigned int* W2f  = (unsigned int*)(ws + WS_W2F);
    float*        W1f  = ws + WS_W1F;
    float*        b1f  = ws + WS_B1F;
    float*        W3p  = ws + WS_W3P;
    float*        b2p  = ws + WS_B2P;
    float*        muA  = ws + WS_MU;
    float*        rsA  = ws + WS_RS;

    stats_partial<<<dim3(KLTOT / 1024, NCHUNK), 256, 0, stream>>>(x, part);
    prep<<<dim3(KLTOT / 4), 256, 0, stream>>>(part, W1, b1, W2, b2, W3,
                                              W2f, W1f, b1f, W3p, b2p, muA, rsA);
    mlp_mfma<<<dim3(KLTOT / 64, B_N / 64), 256, 0, stream>>>(
        x, W2f, W1f, b1f, W3p, b2p, b3, muA, rsA, out);
}

// Round 3
// 42.528 us; speedup vs baseline: 1.2146x; 1.2146x over previous
//
#include <hip/hip_runtime.h>
#include <hip/hip_bf16.h>

typedef short  short8 __attribute__((ext_vector_type(8)));
typedef float  f32x4  __attribute__((ext_vector_type(4)));

#define B_N     2048
#define KLTOT   2048
#define NCHUNK  128
#define CHUNK_ROWS 16      // B_N / NCHUNK

// ---- workspace layout (float-sized slots) ----
#define WS_PART  0                         // 128*2048*2 = 524288
#define WS_W2F   (WS_PART + 524288)        // 2048*256 uints
#define WS_W1F   (WS_W2F + 524288)         // 2048*32
#define WS_B1F   (WS_W1F + 65536)          // 2048*32
#define WS_W3P   (WS_B1F + 65536)          // 2048*16
#define WS_B2P   (WS_W3P + 32768)          // 2048*16
#define WS_MU    (WS_B2P + 32768)          // 2048
#define WS_RS    (WS_MU + 2048)            // 2048

__device__ __forceinline__ unsigned int bfb(float f) {
    union { __hip_bfloat16 h; unsigned short u; } cv;
    cv.h = __float2bfloat16(f);
    return (unsigned int)cv.u;
}

// packed f32->bf16x2 (RNE), single HW instruction on gfx950
__device__ __forceinline__ unsigned int cvtpk(float lo, float hi) {
    unsigned int r;
    asm("v_cvt_pk_bf16_f32 %0, %1, %2" : "=v"(r) : "v"(lo), "v"(hi));
    return r;
}

// ---------------- stats: partial sums over batch chunks ----------------
__global__ __launch_bounds__(256) void stats_partial(const float* __restrict__ x,
                                                     float* __restrict__ part) {
    int c4 = blockIdx.x * 256 + threadIdx.x;          // 0..511 (col groups of 4)
    int chunk = blockIdx.y;                           // 0..127
    const float4* p = (const float4*)(x + (size_t)(chunk * CHUNK_ROWS) * KLTOT) + c4;
    float4 s = {0.f, 0.f, 0.f, 0.f}, s2 = {0.f, 0.f, 0.f, 0.f};
#pragma unroll
    for (int r = 0; r < CHUNK_ROWS; ++r) {
        float4 v = p[(size_t)r * (KLTOT / 4)];
        s.x += v.x; s.y += v.y; s.z += v.z; s.w += v.w;
        s2.x = fmaf(v.x, v.x, s2.x); s2.y = fmaf(v.y, v.y, s2.y);
        s2.z = fmaf(v.z, v.z, s2.z); s2.w = fmaf(v.w, v.w, s2.w);
    }
    float4* o = (float4*)(part + ((size_t)chunk * KLTOT + (size_t)c4 * 4) * 2);
    float4 o0 = {s.x, s2.x, s.y, s2.y};
    float4 o1 = {s.z, s2.z, s.w, s2.w};
    o[0] = o0;
    o[1] = o1;
}

// ---------------- prep: finalize stats + pack MFMA-ready weight fragments ----------------
__global__ __launch_bounds__(256) void prep(
    const float* __restrict__ part,
    const float* __restrict__ W1, const float* __restrict__ b1,
    const float* __restrict__ W2, const float* __restrict__ b2,
    const float* __restrict__ W3,
    unsigned int* __restrict__ W2f, float* __restrict__ W1f, float* __restrict__ b1f,
    float* __restrict__ W3p, float* __restrict__ b2p,
    float* __restrict__ muA, float* __restrict__ rsA)
{
    __shared__ float sW2[4][224];
    const int tid = threadIdx.x;
    const int wv = tid >> 6, l = tid & 63;
    const int col = blockIdx.x * 4 + wv;

    // ---- stats finalize: 128 chunks = 2 per lane + full 64-lane butterfly ----
    {
        size_t base0 = ((size_t)l * KLTOT + col) * 2;
        size_t base1 = ((size_t)(l + 64) * KLTOT + col) * 2;
        float s  = part[base0]     + part[base1];
        float s2 = part[base0 + 1] + part[base1 + 1];
        for (int m = 1; m < 64; m <<= 1) {
            s  += __shfl_xor(s,  m, 64);
            s2 += __shfl_xor(s2, m, 64);
        }
        if (l == 0) {
            float mu  = s / (float)B_N;
            float var = fmaxf(s2 / (float)B_N - mu * mu, 0.f);
            muA[col] = mu;
            rsA[col] = 1.f / (sqrtf(var) + 1e-8f);
        }
    }

    // ---- stage this column's W2 (18x12 = 216 floats = 54 float4) ----
    const float* w2c = W2 + (size_t)col * 216;
    if (l < 54) *(float4*)&sW2[wv][l * 4] = ((const float4*)w2c)[l];
    __syncthreads();

    // ---- W2^T fragment (A-operand): A[row=j][k=h], zero-padded, bf16-packed ----
#pragma unroll
    for (int q = 0; q < 4; ++q) {
        int d = q * 64 + l;
        unsigned int u[2];
#pragma unroll
        for (int half = 0; half < 2; ++half) {
            int idx = d * 2 + half;
            int g = idx >> 7, j = (idx >> 3) & 15, e = idx & 7;
            int h = g * 8 + e;
            float v = (h < 18 && j < 12) ? sW2[wv][h * 12 + j] : 0.f;
            u[half] = bfb(v);
        }
        W2f[(size_t)col * 256 + d] = u[0] | (u[1] << 16);
    }

    // ---- padded f32 copies of W1/b1 (18->32) and W3/b2 (12->16) ----
    if (l < 32) {
        W1f[(size_t)col * 32 + l] = (l < 18) ? W1[(size_t)col * 18 + l] : 0.f;
        b1f[(size_t)col * 32 + l] = (l < 18) ? b1[(size_t)col * 18 + l] : 0.f;
    }
    if (l < 16) {
        W3p[(size_t)col * 16 + l] = (l < 12) ? W3[(size_t)col * 12 + l] : 0.f;
        b2p[(size_t)col * 16 + l] = (l < 12) ? b2[(size_t)col * 12 + l] : 0.f;
    }
}

// ---------------- main MFMA kernel ----------------
// block = 256 thr (4 waves). tile: 64 cols x 64 batch rows. wave: 16 cols x 4 rowblocks.
// per (col, rowblock): D = W2^T(16j x 32h) * h1^T(32h x 16b) + b2   [swapped operands]
__global__ __launch_bounds__(256, 4) void mlp_mfma(
    const float* __restrict__ x,
    const unsigned int* __restrict__ W2f,
    const float* __restrict__ W1f, const float* __restrict__ b1f,
    const float* __restrict__ W3p, const float* __restrict__ b2p,
    const float* __restrict__ b3,
    const float* __restrict__ muA, const float* __restrict__ rsA,
    float* __restrict__ out)
{
    __shared__ float sxs[64 * 68];            // [b][col], pad 68 (2-way banks only)
    const int tid = threadIdx.x;
    const int kl0 = blockIdx.x * 64;
    const int b0  = blockIdx.y * 64;

    // ---- stage standardized x tile [64 b][64 cols] ----
    {
        const int c4 = tid & 15, r0 = tid >> 4;
        f32x4 mu4 = *(const f32x4*)(muA + kl0 + c4 * 4);
        f32x4 rs4 = *(const f32x4*)(rsA + kl0 + c4 * 4);
#pragma unroll
        for (int p = 0; p < 4; ++p) {
            int r = r0 + p * 16;
            f32x4 v = *(const f32x4*)(x + (size_t)(b0 + r) * KLTOT + kl0 + c4 * 4);
            f32x4 o;
#pragma unroll
            for (int e = 0; e < 4; ++e) o[e] = (v[e] - mu4[e]) * rs4[e];
            *(f32x4*)&sxs[r * 68 + c4 * 4] = o;
        }
    }
    __syncthreads();

    const int w = tid >> 6, l = tid & 63;
    const int g = l >> 4, lj = l & 15;

#pragma unroll 1
    for (int cc = 0; cc < 16; ++cc) {
        const int col = kl0 + w * 16 + cc;
        const int colloc = w * 16 + cc;

        short8 afrag = *(const short8*)(W2f + (size_t)col * 256 + (g * 16 + lj) * 4);
        f32x4 w1a = *(const f32x4*)(W1f + (size_t)col * 32 + g * 8);
        f32x4 w1b = *(const f32x4*)(W1f + (size_t)col * 32 + g * 8 + 4);
        f32x4 b1a = *(const f32x4*)(b1f + (size_t)col * 32 + g * 8);
        f32x4 b1b = *(const f32x4*)(b1f + (size_t)col * 32 + g * 8 + 4);
        f32x4 w3r = *(const f32x4*)(W3p + (size_t)col * 16 + g * 4);
        f32x4 b2r = *(const f32x4*)(b2p + (size_t)col * 16 + g * 4);
        float b3v = b3[col];

#pragma unroll
        for (int rb = 0; rb < 4; ++rb) {
            float xsv = sxs[(rb * 16 + lj) * 68 + colloc];

            float h[8];
#pragma unroll
            for (int e = 0; e < 4; ++e) h[e]     = fmaxf(fmaf(xsv, w1a[e], b1a[e]), 0.f);
#pragma unroll
            for (int e = 0; e < 4; ++e) h[4 + e] = fmaxf(fmaf(xsv, w1b[e], b1b[e]), 0.f);

            union { unsigned int u[4]; short8 s; } bf;
#pragma unroll
            for (int q = 0; q < 4; ++q) bf.u[q] = cvtpk(h[2 * q], h[2 * q + 1]);

            f32x4 acc = { b2r[0], b2r[1], b2r[2], b2r[3] };   // C-in = b2 (free bias)
            acc = __builtin_amdgcn_mfma_f32_16x16x32_bf16(afrag, bf.s, acc, 0, 0, 0);

            float pp = 0.f;
#pragma unroll
            for (int r = 0; r < 4; ++r)
                pp = fmaf(fmaxf(acc[r], 0.f), w3r[r], pp);
            pp += __shfl_xor(pp, 16, 64);
            pp += __shfl_xor(pp, 32, 64);

            if (l < 16)                                   // write result back in place
                sxs[(rb * 16 + l) * 68 + colloc] = pp + b3v;
        }
    }
    __syncthreads();

    // ---- coalesced float4 store of the 64x64 tile ----
#pragma unroll
    for (int p = 0; p < 4; ++p) {
        int idx = p * 256 + tid;
        int b = idx >> 4, c4 = idx & 15;
        f32x4 v = *(const f32x4*)&sxs[b * 68 + c4 * 4];
        *(f32x4*)(out + (size_t)(b0 + b) * KLTOT + kl0 + c4 * 4) = v;
    }
}

extern "C" void kernel_launch(void* const* d_in, const int* in_sizes, int n_in,
                              void* d_out, int out_size, void* d_ws, size_t ws_size,
                              hipStream_t stream) {
    const float* x  = (const float*)d_in[0];
    const float* W1 = (const float*)d_in[1];
    const float* b1 = (const float*)d_in[2];
    const float* W2 = (const float*)d_in[3];
    const float* b2 = (const float*)d_in[4];
    const float* W3 = (const float*)d_in[5];
    const float* b3 = (const float*)d_in[6];
    float* out = (float*)d_out;

    float* ws = (float*)d_ws;
    float*        part = ws + WS_PART;
    unsigned int* W2f  = (unsigned int*)(ws + WS_W2F);
    float*        W1f  = ws + WS_W1F;
    float*        b1f  = ws + WS_B1F;
    float*        W3p  = ws + WS_W3P;
    float*        b2p  = ws + WS_B2P;
    float*        muA  = ws + WS_MU;
    float*        rsA  = ws + WS_RS;

    stats_partial<<<dim3(KLTOT / 1024, NCHUNK), 256, 0, stream>>>(x, part);
    prep<<<dim3(KLTOT / 4), 256, 0, stream>>>(part, W1, b1, W2, b2, W3,
                                              W2f, W1f, b1f, W3p, b2p, muA, rsA);
    mlp_mfma<<<dim3(KLTOT / 64, B_N / 64), 256, 0, stream>>>(
        x, W2f, W1f, b1f, W3p, b2p, b3, muA, rsA, out);
}